// Round 1
// 310.854 us; speedup vs baseline: 1.0973x; 1.0973x over previous
//
#include <hip/hip_runtime.h>
#include <cstdint>
#include <cstddef>

typedef unsigned short u16;
typedef __attribute__((ext_vector_type(8))) short short8;      // 8 bf16 (4 VGPRs) MFMA operand
typedef __attribute__((ext_vector_type(4))) float f32x4;       // MFMA 16x16 accumulator
typedef __attribute__((ext_vector_type(4))) float float4v;
typedef __attribute__((ext_vector_type(4))) unsigned short us4;

#define NEMBD 1024
#define NHEADS 16
#define HDIM 64
#define BB 8
#define LL 1024
#define MTOT (BB * LL)

// ---- ws layout (u16 offsets) ----
#define OFF_W 0                       // 4 weight matrices, 1<<20 u16 each (Wq,Wk,Wv,Wp)
#define OFF_B (4u << 20)              // 4 biases, 1024 u16 each (bq,bk,bv,bp)
#define OFF_QB (OFF_B + 4096)         // Q projection / attn output, 1<<23 u16
#define OFF_X (OFF_QB + (1u << 23))   // optional bf16 copies of query,key,value
#define WS_NEED_PRE ((size_t)(OFF_X + 3u * (1u << 23)) * 2)  // 75,505,664 B

static __device__ __forceinline__ float bf2f(u16 h) {
    union { unsigned u; float f; } x; x.u = ((unsigned)h) << 16; return x.f;
}
static __device__ __forceinline__ u16 f2bf(float f) {
    union { unsigned u; float f; } x; x.f = f;
    unsigned u = x.u; u += 0x7fffu + ((u >> 16) & 1u);
    return (u16)(u >> 16);
}

// async global->LDS, 16B per lane; LDS dest = wave-uniform base + lane*16
static __device__ __forceinline__ void async_ld16(const void* g, void* lds_base) {
    __builtin_amdgcn_global_load_lds(
        (const __attribute__((address_space(1))) unsigned int*)g,
        (__attribute__((address_space(3))) unsigned int*)lds_base, 16, 0, 0);
}
#define WAIT_ALL() asm volatile("s_waitcnt vmcnt(0) lgkmcnt(0)" ::: "memory")

// ------------------------------------------------------------------
// fp32 -> bf16 conversion pass (1024 elems per block).
__global__ __launch_bounds__(256) void cvt_all(
    const float* __restrict__ Wq, const float* __restrict__ Wk,
    const float* __restrict__ Wv, const float* __restrict__ Wp,
    const float* __restrict__ bq, const float* __restrict__ bk,
    const float* __restrict__ bv, const float* __restrict__ bp,
    const float* __restrict__ xq, const float* __restrict__ xk,
    const float* __restrict__ xv, u16* __restrict__ ws)
{
    int blk = blockIdx.x;
    const float* src; u16* dst; float scale = 1.f;
    if (blk < 1024)      { src = Wq; dst = ws + OFF_W;               scale = 0.125f; }
    else if (blk < 2048) { src = Wk; dst = ws + OFF_W + (1u << 20);  blk -= 1024; }
    else if (blk < 3072) { src = Wv; dst = ws + OFF_W + (2u << 20);  blk -= 2048; }
    else if (blk < 4096) { src = Wp; dst = ws + OFF_W + (3u << 20);  blk -= 3072; }
    else if (blk < 4100) {
        int wb = blk - 4096;
        src = (wb == 0) ? bq : (wb == 1) ? bk : (wb == 2) ? bv : bp;
        dst = ws + OFF_B + wb * 1024; scale = (wb == 0) ? 0.125f : 1.f; blk = 0;
    }
    else if (blk < 12292) { src = xq; dst = ws + OFF_X;               blk -= 4100; }
    else if (blk < 20484) { src = xk; dst = ws + OFF_X + (1u << 23);  blk -= 12292; }
    else                  { src = xv; dst = ws + OFF_X + (2u << 23);  blk -= 20484; }
    const int i = blk * 1024 + threadIdx.x * 4;
    float4v f = *(const float4v*)&src[i];
    us4 o;
#pragma unroll
    for (int j = 0; j < 4; j++) o[j] = f2bf(f[j] * scale);
    *(us4*)&dst[i] = o;
}

// ------------------------------------------------------------------
// Y[m][n] = sum_k X[m][k]*W[n][k] + bias[n]. M=8192, N=K=1024. BK=64,
// XOR-8 chunk swizzle on As/Bs (chunk c of row r stored at c^(r&7)).
// vtrans: write V^T layout [b][h][d][key].
template <typename TX, typename TY>
static __device__ __forceinline__ void gemm_body64(
    const TX* __restrict__ X, const u16* __restrict__ W,
    const u16* __restrict__ bias, TY* __restrict__ Y, int vtrans,
    u16* As, u16* Bs)   // each 128*64 u16
{
    constexpr int K = NEMBD, N = NEMBD;
    const int t = threadIdx.x;
    const int wave = t >> 6, lane = t & 63;
    const int quad = lane >> 4, l16 = lane & 15;
    const int m0 = blockIdx.y * 128, n0 = blockIdx.x * 128;
    const int wm = (wave >> 1) * 64, wn = (wave & 1) * 64;
    const int rsub = lane >> 3;                 // staging row within 8-row group
    const int csw = ((lane & 7) ^ rsub) * 8;    // swizzled source col (u16)
    const int swr = l16 & 7;                    // read swizzle key (row&7 == l16&7)
    const int frow = t >> 1, fc0 = (t & 1) * 4; // fp32 manual staging

    f32x4 acc[4][4];
#pragma unroll
    for (int i = 0; i < 4; i++)
#pragma unroll
        for (int j = 0; j < 4; j++) acc[i][j] = (f32x4){0.f, 0.f, 0.f, 0.f};

    for (int k0 = 0; k0 < K; k0 += 64) {
        if constexpr (__is_same(TX, u16)) {
#pragma unroll
            for (int j = 0; j < 4; j++) {
                const int g = wave * 4 + j;     // 8-row group
                async_ld16(X + (size_t)(m0 + g * 8 + rsub) * K + k0 + csw, &As[g * 8 * 64]);
            }
        } else {
#pragma unroll
            for (int c = 0; c < 4; c++) {
                const int lc = fc0 + c;
                float4v f0 = *(const float4v*)&X[(size_t)(m0 + frow) * K + k0 + lc * 8];
                float4v f1 = *(const float4v*)&X[(size_t)(m0 + frow) * K + k0 + lc * 8 + 4];
                __align__(16) u16 tmp[8];
#pragma unroll
                for (int j = 0; j < 4; j++) { tmp[j] = f2bf(f0[j]); tmp[4 + j] = f2bf(f1[j]); }
                *(short8*)&As[frow * 64 + (lc ^ (frow & 7)) * 8] = *(const short8*)tmp;
            }
        }
#pragma unroll
        for (int j = 0; j < 4; j++) {
            const int g = wave * 4 + j;
            async_ld16(W + (size_t)(n0 + g * 8 + rsub) * K + k0 + csw, &Bs[g * 8 * 64]);
        }
        WAIT_ALL();
        __syncthreads();

#pragma unroll
        for (int h = 0; h < 2; h++) {           // two 32-wide k-halves
            short8 a[4], b[4];
#pragma unroll
            for (int i = 0; i < 4; i++) {
                a[i] = *(const short8*)&As[(wm + i * 16 + l16) * 64 + (((h * 4 + quad) ^ swr) * 8)];
                b[i] = *(const short8*)&Bs[(wn + i * 16 + l16) * 64 + (((h * 4 + quad) ^ swr) * 8)];
            }
#pragma unroll
            for (int i = 0; i < 4; i++)
#pragma unroll
                for (int j = 0; j < 4; j++)
                    acc[i][j] = __builtin_amdgcn_mfma_f32_16x16x32_bf16(a[i], b[j], acc[i][j], 0, 0, 0);
        }
        __syncthreads();
    }

    // C/D layout: col=lane&15, row=quad*4+reg
    if (vtrans) {
        u16* VT = (u16*)Y;
#pragma unroll
        for (int j = 0; j < 4; j++) {
            const int n = n0 + wn + j * 16 + l16;
            const float bn = bf2f(bias[n]);
            const int h = n >> 6, d = n & 63;
#pragma unroll
            for (int i = 0; i < 4; i++) {
                const int mb = m0 + wm + i * 16 + quad * 4;
                const int b = mb >> 10, key = mb & 1023;
                us4 pack;
#pragma unroll
                for (int r = 0; r < 4; r++) pack[r] = f2bf(acc[i][j][r] + bn);
                *(us4*)&VT[(size_t)(b * 16 + h) * 65536 + d * 1024 + key] = pack;
            }
        }
    } else {
#pragma unroll
        for (int j = 0; j < 4; j++) {
            const int n = n0 + wn + j * 16 + l16;
            const float bn = bf2f(bias[n]);
#pragma unroll
            for (int i = 0; i < 4; i++) {
                const int mb = m0 + wm + i * 16 + quad * 4;
#pragma unroll
                for (int r = 0; r < 4; r++) {
                    float v = acc[i][j][r] + bn;
                    if constexpr (__is_same(TY, u16)) Y[(size_t)(mb + r) * N + n] = f2bf(v);
                    else                              Y[(size_t)(mb + r) * N + n] = v;
                }
            }
        }
    }
}

// QKV, bf16-X path. z: 0=Q->qb (pre-scaled W), 1=K->kb, 2=V->vtg (transposed)
__global__ __launch_bounds__(256) void gemm_qkv_b(
    const u16* __restrict__ xq, const u16* __restrict__ xk, const u16* __restrict__ xv,
    const u16* __restrict__ ws, u16* __restrict__ qb, u16* __restrict__ kb,
    u16* __restrict__ vtg)
{
    __shared__ __align__(16) u16 As[128 * 64];
    __shared__ __align__(16) u16 Bs[128 * 64];
    const int z = blockIdx.z;
    const u16* X = (z == 0) ? xq : (z == 1) ? xk : xv;
    const u16* W = ws + OFF_W + (size_t)z * (1u << 20);
    const u16* bias = ws + OFF_B + z * 1024;
    u16* Y = (z == 0) ? qb : (z == 1) ? kb : vtg;
    gemm_body64<u16, u16>(X, W, bias, Y, z == 2 ? 1 : 0, As, Bs);
}

// QKV, fp32-X fallback (in-GEMM convert)
__global__ __launch_bounds__(256) void gemm_qkv_f(
    const float* __restrict__ xq, const float* __restrict__ xk, const float* __restrict__ xv,
    const u16* __restrict__ ws, u16* __restrict__ qb, u16* __restrict__ kb,
    u16* __restrict__ vtg)
{
    __shared__ __align__(16) u16 As[128 * 64];
    __shared__ __align__(16) u16 Bs[128 * 64];
    const int z = blockIdx.z;
    const float* X = (z == 0) ? xq : (z == 1) ? xk : xv;
    const u16* W = ws + OFF_W + (size_t)z * (1u << 20);
    const u16* bias = ws + OFF_B + z * 1024;
    u16* Y = (z == 0) ? qb : (z == 1) ? kb : vtg;
    gemm_body64<float, u16>(X, W, bias, Y, z == 2 ? 1 : 0, As, Bs);
}

// Output projection: bf16 X, fp32 output
__global__ __launch_bounds__(256) void gemm_out_k(
    const u16* __restrict__ X, const u16* __restrict__ ws, float* __restrict__ Y)
{
    __shared__ __align__(16) u16 As[128 * 64];
    __shared__ __align__(16) u16 Bs[128 * 64];
    gemm_body64<u16, float>(X, ws + OFF_W + (size_t)3 * (1u << 20), ws + OFF_B + 3 * 1024,
                            Y, 0, As, Bs);
}

// ------------------------------------------------------------------
// Flash attention v5: work-balanced query-tile PAIRING + double-buffered
// prefetch. Block p (0..3) handles query tiles qtA=p and qtB=7-p: total
// compute = 18 tile-units for every block (perfect balance), and both
// tiles share each staged K/V tile (A's key range is a subset of B's).
// 2-phase pipeline (T3-minimum): stage kt+1 into buf^1 BEFORE computing
// kt from buf, single vmcnt(0)+barrier per iter -> HBM latency hides
// under QK/softmax/PV. s_setprio(1) around PV MFMA cluster.
// LDS 68 KiB -> 2 blocks/CU; __launch_bounds__(256,2) caps VGPR at 256.
__global__ __launch_bounds__(256, 2) void attn_fused(
    const u16* __restrict__ Qp, const u16* __restrict__ Kp,
    const u16* __restrict__ Vtg, u16* __restrict__ Yp)
{
    __shared__ __align__(16) u16 Kl[2][64 * 64];    // [buf][key][d], chunk-swizzled
    __shared__ __align__(16) u16 Vt[2][64 * 64];    // [buf][d][key], chunk-swizzled
    __shared__ __align__(16) u16 Pl[4 * 64 * 72];   // per-wave P: rows 0-31 tile A, 32-63 tile B

    const int t = threadIdx.x;
    const int wave = t >> 6, lane = t & 63;
    const int quad = lane >> 4, l16 = lane & 15;
    const int bh = blockIdx.y;
    const int b = bh >> 4, h = bh & 15;
    const int p = blockIdx.x;                       // pair index 0..3
    const int qtA = p, qtB = 7 - p;
    const int q0A = qtA * 128 + wave * 32;          // this wave's 32 queries, tile A
    const int q0B = qtB * 128 + wave * 32;          // and tile B

    const u16* Qb = Qp + (size_t)b * LL * NEMBD + h * HDIM;
    const u16* Kb = Kp + (size_t)b * LL * NEMBD + h * HDIM;
    const u16* Vb = Vtg + (size_t)bh * 65536;       // [d][key]

    // Q A-frags for both tiles: A[m=l16][k=quad*8+j]
    short8 aqA[2][2], aqB[2][2];
#pragma unroll
    for (int m = 0; m < 2; m++) {
        aqA[m][0] = *(const short8*)(Qb + (size_t)(q0A + m * 16 + l16) * NEMBD + quad * 8);
        aqA[m][1] = *(const short8*)(Qb + (size_t)(q0A + m * 16 + l16) * NEMBD + 32 + quad * 8);
        aqB[m][0] = *(const short8*)(Qb + (size_t)(q0B + m * 16 + l16) * NEMBD + quad * 8);
        aqB[m][1] = *(const short8*)(Qb + (size_t)(q0B + m * 16 + l16) * NEMBD + 32 + quad * 8);
    }

    f32x4 accA[2][4], accB[2][4];
#pragma unroll
    for (int m = 0; m < 2; m++)
#pragma unroll
        for (int n = 0; n < 4; n++) {
            accA[m][n] = (f32x4){0.f, 0.f, 0.f, 0.f};
            accB[m][n] = (f32x4){0.f, 0.f, 0.f, 0.f};
        }
    float lsA[2][4] = {{0.f, 0.f, 0.f, 0.f}, {0.f, 0.f, 0.f, 0.f}};
    float lsB[2][4] = {{0.f, 0.f, 0.f, 0.f}, {0.f, 0.f, 0.f, 0.f}};

    const int rsub = lane >> 3;
    const int csw8 = ((lane & 7) ^ rsub) * 8;
    const int swr = l16 & 7;
    u16* pw = &Pl[wave * 64 * 72];

    const int ktiles  = 2 * qtB + 2;                // B covers the full key range
    const int ktilesA = 2 * qtA + 2;                // A active only this far

    // stage one 64-key K/V tile into buffer bufi (each wave: 16 rows of each)
    auto stageKV = [&](int kbase, int bufi) {
#pragma unroll
        for (int j = 0; j < 2; j++) {
            const int g0 = wave * 16 + j * 8;       // 8-row group base
            async_ld16(Kb + (size_t)(kbase + g0 + rsub) * NEMBD + csw8, &Kl[bufi][g0 * 64]);
            async_ld16(Vb + (size_t)(g0 + rsub) * LL + kbase + csw8, &Vt[bufi][g0 * 64]);
        }
    };

    // QK^T + exp + P write for one tile (Pl region pwT)
    auto qk = [&](const short8 (&aq)[2][2], int q0w, int kbase, const u16* KlC,
                  u16* pwT, float (&lsum)[2][4]) {
#pragma unroll
        for (int m = 0; m < 2; m++) {
            const int qlo = q0w + m * 16;
            if (kbase > qlo + 15) continue;         // fully masked (wave-uniform)
            const bool dg = (kbase + 63 > qlo);
#pragma unroll
            for (int s = 0; s < 4; s++) {
                const int key = s * 16 + l16;
                const short8 bk0 = *(const short8*)&KlC[key * 64 + ((quad ^ swr) * 8)];
                const short8 bk1 = *(const short8*)&KlC[key * 64 + (((quad + 4) ^ swr) * 8)];
                f32x4 ss = (f32x4){0.f, 0.f, 0.f, 0.f};
                ss = __builtin_amdgcn_mfma_f32_16x16x32_bf16(aq[m][0], bk0, ss, 0, 0, 0);
                ss = __builtin_amdgcn_mfma_f32_16x16x32_bf16(aq[m][1], bk1, ss, 0, 0, 0);
#pragma unroll
                for (int r = 0; r < 4; r++) {
                    float e = __expf(ss[r]);
                    if (dg && (kbase + key > qlo + quad * 4 + r)) e = 0.f;
                    lsum[m][r] += e;
                    pwT[(m * 16 + quad * 4 + r) * 72 + key] = f2bf(e);
                }
            }
        }
    };

    // P x V accumulate for one tile
    auto pv = [&](f32x4 (&acc)[2][4], int q0w, int kbase, const u16* pwT,
                  const short8 (&bv)[4][2]) {
#pragma unroll
        for (int m = 0; m < 2; m++) {
            if (kbase > q0w + m * 16 + 15) continue;
            const short8 ap0 = *(const short8*)&pwT[(m * 16 + l16) * 72 + quad * 8];
            const short8 ap1 = *(const short8*)&pwT[(m * 16 + l16) * 72 + 32 + quad * 8];
#pragma unroll
            for (int n = 0; n < 4; n++) {
                acc[m][n] = __builtin_amdgcn_mfma_f32_16x16x32_bf16(ap0, bv[n][0], acc[m][n], 0, 0, 0);
                acc[m][n] = __builtin_amdgcn_mfma_f32_16x16x32_bf16(ap1, bv[n][1], acc[m][n], 0, 0, 0);
            }
        }
    };

    // prologue: stage kt=0 into buf 0
    stageKV(0, 0);
    WAIT_ALL();
    __syncthreads();

    int cur = 0;
    for (int kt = 0; kt < ktiles; kt++) {
        const int kbase = kt * 64;
        // prefetch next tile into the other buffer BEFORE compute
        if (kt + 1 < ktiles) stageKV(kbase + 64, cur ^ 1);

        const u16* KlC = &Kl[cur][0];
        const u16* VtC = &Vt[cur][0];

        qk(aqB, q0B, kbase, KlC, pw + 32 * 72, lsB);
        if (kt < ktilesA) qk(aqA, q0A, kbase, KlC, pw, lsA);
        asm volatile("s_waitcnt lgkmcnt(0)" ::: "memory");  // wave-private P write->read

        const bool actB = (kbase <= q0B + 31);
        const bool actA = (kt < ktilesA) && (kbase <= q0A + 31);
        if (actA || actB) {
            short8 bv[4][2];
#pragma unroll
            for (int n = 0; n < 4; n++) {
                const int drow = (n * 16 + l16) * 64;
                bv[n][0] = *(const short8*)&VtC[drow + ((quad ^ swr) * 8)];
                bv[n][1] = *(const short8*)&VtC[drow + (((quad + 4) ^ swr) * 8)];
            }
            __builtin_amdgcn_s_setprio(1);
            if (actB) pv(accB, q0B, kbase, pw + 32 * 72, bv);
            if (actA) pv(accA, q0A, kbase, pw, bv);
            __builtin_amdgcn_s_setprio(0);
        }

        WAIT_ALL();                                 // drain prefetch (overlapped w/ compute)
        __syncthreads();                            // all waves done with buf[cur]
        cur ^= 1;
    }

    u16* Yb = Yp + (size_t)b * LL * NEMBD + h * HDIM;
    auto epi = [&](f32x4 (&acc)[2][4], float (&lsum)[2][4], int q0w) {
#pragma unroll
        for (int m = 0; m < 2; m++) {
#pragma unroll
            for (int r = 0; r < 4; r++) {
                float lr = lsum[m][r];
                lr += __shfl_xor(lr, 1); lr += __shfl_xor(lr, 2);
                lr += __shfl_xor(lr, 4); lr += __shfl_xor(lr, 8);
                const float inv = 1.f / lr;
                const int q = q0w + m * 16 + quad * 4 + r;
#pragma unroll
                for (int n = 0; n < 4; n++)
                    Yb[(size_t)q * NEMBD + n * 16 + l16] = f2bf(acc[m][n][r] * inv);
            }
        }
    };
    epi(accA, lsA, q0A);
    epi(accB, lsB, q0B);
}

// ------------------------------------------------------------------
extern "C" void kernel_launch(void* const* d_in, const int* in_sizes, int n_in,
                              void* d_out, int out_size, void* d_ws, size_t ws_size,
                              hipStream_t stream)
{
    const float* key   = (const float*)d_in[0];
    const float* value = (const float*)d_in[1];
    const float* query = (const float*)d_in[2];
    const float* Wk = (const float*)d_in[3];
    const float* bk = (const float*)d_in[4];
    const float* Wq = (const float*)d_in[5];
    const float* bq = (const float*)d_in[6];
    const float* Wv = (const float*)d_in[7];
    const float* bv = (const float*)d_in[8];
    const float* Wp = (const float*)d_in[9];
    const float* bp = (const float*)d_in[10];

    u16* ws = (u16*)d_ws;
    u16* qb = ws + OFF_QB;                       // Q proj; also attn output (alias-safe)
    u16* kb = (u16*)d_out;                       // K proj in d_out
    u16* vtg = (u16*)d_out + (1u << 23);         // V^T [b][h][d][key] in d_out

    const bool preX = ws_size >= WS_NEED_PRE;    // constant across calls -> graph-safe

    cvt_all<<<preX ? 28676 : 4100, 256, 0, stream>>>(
        Wq, Wk, Wv, Wp, bq, bk, bv, bp, query, key, value, ws);

    if (preX) {
        const u16* xq = ws + OFF_X;
        const u16* xk = ws + OFF_X + (1u << 23);
        const u16* xv = ws + OFF_X + (2u << 23);
        gemm_qkv_b<<<dim3(8, 64, 3), 256, 0, stream>>>(xq, xk, xv, ws, qb, kb, vtg);
    } else {
        gemm_qkv_f<<<dim3(8, 64, 3), 256, 0, stream>>>(query, key, value, ws, qb, kb, vtg);
    }

    attn_fused<<<dim3(4, 128), 256, 0, stream>>>(qb, kb, vtg, qb);

    gemm_out_k<<<dim3(8, 64), 256, 0, stream>>>(qb, ws, (float*)d_out);
}

// Round 2
// 293.389 us; speedup vs baseline: 1.1626x; 1.0595x over previous
//
#include <hip/hip_runtime.h>
#include <cstdint>
#include <cstddef>

typedef unsigned short u16;
typedef __attribute__((ext_vector_type(8))) short short8;      // 8 bf16 (4 VGPRs) MFMA operand
typedef __attribute__((ext_vector_type(4))) float f32x4;       // MFMA 16x16 accumulator
typedef __attribute__((ext_vector_type(4))) float float4v;
typedef __attribute__((ext_vector_type(4))) unsigned short us4;

#define NEMBD 1024
#define NHEADS 16
#define HDIM 64
#define BB 8
#define LL 1024
#define MTOT (BB * LL)

// ---- ws layout (u16 offsets) ----
#define OFF_W 0                       // 4 weight matrices, 1<<20 u16 each (Wq,Wk,Wv,Wp)
#define OFF_B (4u << 20)              // 4 biases, 1024 u16 each (bq,bk,bv,bp)
#define OFF_QB (OFF_B + 4096)         // Q projection / attn output, 1<<23 u16
#define OFF_X (OFF_QB + (1u << 23))   // optional bf16 copies of query,key,value
#define WS_NEED_PRE ((size_t)(OFF_X + 3u * (1u << 23)) * 2)  // 75,505,664 B

static __device__ __forceinline__ float bf2f(u16 h) {
    union { unsigned u; float f; } x; x.u = ((unsigned)h) << 16; return x.f;
}
static __device__ __forceinline__ u16 f2bf(float f) {
    union { unsigned u; float f; } x; x.f = f;
    unsigned u = x.u; u += 0x7fffu + ((u >> 16) & 1u);
    return (u16)(u >> 16);
}

// async global->LDS, 16B per lane; LDS dest = wave-uniform base + lane*16
static __device__ __forceinline__ void async_ld16(const void* g, void* lds_base) {
    __builtin_amdgcn_global_load_lds(
        (const __attribute__((address_space(1))) unsigned int*)g,
        (__attribute__((address_space(3))) unsigned int*)lds_base, 16, 0, 0);
}
#define WAIT_ALL() asm volatile("s_waitcnt vmcnt(0) lgkmcnt(0)" ::: "memory")

// ------------------------------------------------------------------
// fp32 -> bf16 conversion pass (1024 elems per block).
__global__ __launch_bounds__(256) void cvt_all(
    const float* __restrict__ Wq, const float* __restrict__ Wk,
    const float* __restrict__ Wv, const float* __restrict__ Wp,
    const float* __restrict__ bq, const float* __restrict__ bk,
    const float* __restrict__ bv, const float* __restrict__ bp,
    const float* __restrict__ xq, const float* __restrict__ xk,
    const float* __restrict__ xv, u16* __restrict__ ws)
{
    int blk = blockIdx.x;
    const float* src; u16* dst; float scale = 1.f;
    if (blk < 1024)      { src = Wq; dst = ws + OFF_W;               scale = 0.125f; }
    else if (blk < 2048) { src = Wk; dst = ws + OFF_W + (1u << 20);  blk -= 1024; }
    else if (blk < 3072) { src = Wv; dst = ws + OFF_W + (2u << 20);  blk -= 2048; }
    else if (blk < 4096) { src = Wp; dst = ws + OFF_W + (3u << 20);  blk -= 3072; }
    else if (blk < 4100) {
        int wb = blk - 4096;
        src = (wb == 0) ? bq : (wb == 1) ? bk : (wb == 2) ? bv : bp;
        dst = ws + OFF_B + wb * 1024; scale = (wb == 0) ? 0.125f : 1.f; blk = 0;
    }
    else if (blk < 12292) { src = xq; dst = ws + OFF_X;               blk -= 4100; }
    else if (blk < 20484) { src = xk; dst = ws + OFF_X + (1u << 23);  blk -= 12292; }
    else                  { src = xv; dst = ws + OFF_X + (2u << 23);  blk -= 20484; }
    const int i = blk * 1024 + threadIdx.x * 4;
    float4v f = *(const float4v*)&src[i];
    us4 o;
#pragma unroll
    for (int j = 0; j < 4; j++) o[j] = f2bf(f[j] * scale);
    *(us4*)&dst[i] = o;
}

// ------------------------------------------------------------------
// Y[m][n] = sum_k X[m][k]*W[n][k] + bias[n]. M=8192, N=K=1024. BK=64,
// XOR-8 chunk swizzle on As/Bs (chunk c of row r stored at c^(r&7)).
// 2-phase double-buffered pipeline: stage k+1 into buf^1 BEFORE computing
// buf, one vmcnt(0)+barrier per K-step (T3-minimum). XCD-aware chunk
// swizzle over the 512-block (x,y) grid: each XCD gets 8 contiguous
// m-panels (X-panel fetched once chip-wide; W L2-fits per XCD).
// vtrans: write V^T layout [b][h][d][key].
template <typename TX, typename TY>
static __device__ __forceinline__ void gemm_body64(
    const TX* __restrict__ X, const u16* __restrict__ W,
    const u16* __restrict__ bias, TY* __restrict__ Y, int vtrans,
    u16* As, u16* Bs)   // each 2 * 128*64 u16 (double-buffered)
{
    constexpr int K = NEMBD, N = NEMBD;
    constexpr int BUF = 128 * 64;
    const int t = threadIdx.x;
    const int wave = t >> 6, lane = t & 63;
    const int quad = lane >> 4, l16 = lane & 15;
    // XCD-aware bijective chunk swizzle (512 = 8 chunks x 64)
    const int flat = blockIdx.x + 8 * blockIdx.y;
    const int swz = (flat & 7) * 64 + (flat >> 3);
    const int m0 = (swz >> 3) * 128, n0 = (swz & 7) * 128;
    const int wm = (wave >> 1) * 64, wn = (wave & 1) * 64;
    const int rsub = lane >> 3;                 // staging row within 8-row group
    const int csw = ((lane & 7) ^ rsub) * 8;    // swizzled source col (u16)
    const int swr = l16 & 7;                    // read swizzle key (row&7 == l16&7)
    const int frow = t >> 1, fc0 = (t & 1) * 4; // fp32 manual staging

    f32x4 acc[4][4];
#pragma unroll
    for (int i = 0; i < 4; i++)
#pragma unroll
        for (int j = 0; j < 4; j++) acc[i][j] = (f32x4){0.f, 0.f, 0.f, 0.f};

    // stage one 128x64 A-tile + B-tile at k0 into buffer bufi
    auto stage = [&](int k0, int bufi) {
        u16* A = As + bufi * BUF;
        u16* Bb = Bs + bufi * BUF;
        if constexpr (__is_same(TX, u16)) {
#pragma unroll
            for (int j = 0; j < 4; j++) {
                const int g = wave * 4 + j;     // 8-row group
                async_ld16(X + (size_t)(m0 + g * 8 + rsub) * K + k0 + csw, &A[g * 8 * 64]);
            }
        } else {
#pragma unroll
            for (int c = 0; c < 4; c++) {
                const int lc = fc0 + c;
                float4v f0 = *(const float4v*)&X[(size_t)(m0 + frow) * K + k0 + lc * 8];
                float4v f1 = *(const float4v*)&X[(size_t)(m0 + frow) * K + k0 + lc * 8 + 4];
                __align__(16) u16 tmp[8];
#pragma unroll
                for (int j = 0; j < 4; j++) { tmp[j] = f2bf(f0[j]); tmp[4 + j] = f2bf(f1[j]); }
                *(short8*)&A[frow * 64 + (lc ^ (frow & 7)) * 8] = *(const short8*)tmp;
            }
        }
#pragma unroll
        for (int j = 0; j < 4; j++) {
            const int g = wave * 4 + j;
            async_ld16(W + (size_t)(n0 + g * 8 + rsub) * K + k0 + csw, &Bb[g * 8 * 64]);
        }
    };

    // prologue
    stage(0, 0);
    WAIT_ALL();
    __syncthreads();

    int cur = 0;
    for (int k0 = 0; k0 < K; k0 += 64) {
        if (k0 + 64 < K) stage(k0 + 64, cur ^ 1);   // prefetch next tile first

        const u16* A = As + cur * BUF;
        const u16* Bb = Bs + cur * BUF;
#pragma unroll
        for (int h = 0; h < 2; h++) {           // two 32-wide k-halves
            short8 a[4], b[4];
#pragma unroll
            for (int i = 0; i < 4; i++) {
                a[i] = *(const short8*)&A[(wm + i * 16 + l16) * 64 + (((h * 4 + quad) ^ swr) * 8)];
                b[i] = *(const short8*)&Bb[(wn + i * 16 + l16) * 64 + (((h * 4 + quad) ^ swr) * 8)];
            }
#pragma unroll
            for (int i = 0; i < 4; i++)
#pragma unroll
                for (int j = 0; j < 4; j++)
                    acc[i][j] = __builtin_amdgcn_mfma_f32_16x16x32_bf16(a[i], b[j], acc[i][j], 0, 0, 0);
        }

        WAIT_ALL();                             // drain prefetch (overlapped w/ MFMA)
        __syncthreads();                        // all waves done reading buf[cur]
        cur ^= 1;
    }

    // C/D layout: col=lane&15, row=quad*4+reg
    if (vtrans) {
        u16* VT = (u16*)Y;
#pragma unroll
        for (int j = 0; j < 4; j++) {
            const int n = n0 + wn + j * 16 + l16;
            const float bn = bf2f(bias[n]);
            const int h = n >> 6, d = n & 63;
#pragma unroll
            for (int i = 0; i < 4; i++) {
                const int mb = m0 + wm + i * 16 + quad * 4;
                const int b = mb >> 10, key = mb & 1023;
                us4 pack;
#pragma unroll
                for (int r = 0; r < 4; r++) pack[r] = f2bf(acc[i][j][r] + bn);
                *(us4*)&VT[(size_t)(b * 16 + h) * 65536 + d * 1024 + key] = pack;
            }
        }
    } else {
#pragma unroll
        for (int j = 0; j < 4; j++) {
            const int n = n0 + wn + j * 16 + l16;
            const float bn = bf2f(bias[n]);
#pragma unroll
            for (int i = 0; i < 4; i++) {
                const int mb = m0 + wm + i * 16 + quad * 4;
#pragma unroll
                for (int r = 0; r < 4; r++) {
                    float v = acc[i][j][r] + bn;
                    if constexpr (__is_same(TY, u16)) Y[(size_t)(mb + r) * N + n] = f2bf(v);
                    else                              Y[(size_t)(mb + r) * N + n] = v;
                }
            }
        }
    }
}

// QKV, bf16-X path. z: 0=Q->qb (pre-scaled W), 1=K->kb, 2=V->vtg (transposed)
__global__ __launch_bounds__(256) void gemm_qkv_b(
    const u16* __restrict__ xq, const u16* __restrict__ xk, const u16* __restrict__ xv,
    const u16* __restrict__ ws, u16* __restrict__ qb, u16* __restrict__ kb,
    u16* __restrict__ vtg)
{
    __shared__ __align__(16) u16 As[2 * 128 * 64];
    __shared__ __align__(16) u16 Bs[2 * 128 * 64];
    const int z = blockIdx.z;
    const u16* X = (z == 0) ? xq : (z == 1) ? xk : xv;
    const u16* W = ws + OFF_W + (size_t)z * (1u << 20);
    const u16* bias = ws + OFF_B + z * 1024;
    u16* Y = (z == 0) ? qb : (z == 1) ? kb : vtg;
    gemm_body64<u16, u16>(X, W, bias, Y, z == 2 ? 1 : 0, As, Bs);
}

// QKV, fp32-X fallback (in-GEMM convert)
__global__ __launch_bounds__(256) void gemm_qkv_f(
    const float* __restrict__ xq, const float* __restrict__ xk, const float* __restrict__ xv,
    const u16* __restrict__ ws, u16* __restrict__ qb, u16* __restrict__ kb,
    u16* __restrict__ vtg)
{
    __shared__ __align__(16) u16 As[2 * 128 * 64];
    __shared__ __align__(16) u16 Bs[2 * 128 * 64];
    const int z = blockIdx.z;
    const float* X = (z == 0) ? xq : (z == 1) ? xk : xv;
    const u16* W = ws + OFF_W + (size_t)z * (1u << 20);
    const u16* bias = ws + OFF_B + z * 1024;
    u16* Y = (z == 0) ? qb : (z == 1) ? kb : vtg;
    gemm_body64<float, u16>(X, W, bias, Y, z == 2 ? 1 : 0, As, Bs);
}

// Output projection: bf16 X, fp32 output
__global__ __launch_bounds__(256) void gemm_out_k(
    const u16* __restrict__ X, const u16* __restrict__ ws, float* __restrict__ Y)
{
    __shared__ __align__(16) u16 As[2 * 128 * 64];
    __shared__ __align__(16) u16 Bs[2 * 128 * 64];
    gemm_body64<u16, float>(X, ws + OFF_W + (size_t)3 * (1u << 20), ws + OFF_B + 3 * 1024,
                            Y, 0, As, Bs);
}

// ------------------------------------------------------------------
// Flash attention v5: work-balanced query-tile PAIRING + double-buffered
// prefetch. Block p (0..3) handles query tiles qtA=p and qtB=7-p: total
// compute = 18 tile-units for every block (perfect balance), and both
// tiles share each staged K/V tile (A's key range is a subset of B's).
// 2-phase pipeline (T3-minimum): stage kt+1 into buf^1 BEFORE computing
// kt from buf, single vmcnt(0)+barrier per iter -> HBM latency hides
// under QK/softmax/PV. s_setprio(1) around PV MFMA cluster.
// LDS 68 KiB -> 2 blocks/CU; __launch_bounds__(256,2) caps VGPR at 256.
__global__ __launch_bounds__(256, 2) void attn_fused(
    const u16* __restrict__ Qp, const u16* __restrict__ Kp,
    const u16* __restrict__ Vtg, u16* __restrict__ Yp)
{
    __shared__ __align__(16) u16 Kl[2][64 * 64];    // [buf][key][d], chunk-swizzled
    __shared__ __align__(16) u16 Vt[2][64 * 64];    // [buf][d][key], chunk-swizzled
    __shared__ __align__(16) u16 Pl[4 * 64 * 72];   // per-wave P: rows 0-31 tile A, 32-63 tile B

    const int t = threadIdx.x;
    const int wave = t >> 6, lane = t & 63;
    const int quad = lane >> 4, l16 = lane & 15;
    const int bh = blockIdx.y;
    const int b = bh >> 4, h = bh & 15;
    const int p = blockIdx.x;                       // pair index 0..3
    const int qtA = p, qtB = 7 - p;
    const int q0A = qtA * 128 + wave * 32;          // this wave's 32 queries, tile A
    const int q0B = qtB * 128 + wave * 32;          // and tile B

    const u16* Qb = Qp + (size_t)b * LL * NEMBD + h * HDIM;
    const u16* Kb = Kp + (size_t)b * LL * NEMBD + h * HDIM;
    const u16* Vb = Vtg + (size_t)bh * 65536;       // [d][key]

    // Q A-frags for both tiles: A[m=l16][k=quad*8+j]
    short8 aqA[2][2], aqB[2][2];
#pragma unroll
    for (int m = 0; m < 2; m++) {
        aqA[m][0] = *(const short8*)(Qb + (size_t)(q0A + m * 16 + l16) * NEMBD + quad * 8);
        aqA[m][1] = *(const short8*)(Qb + (size_t)(q0A + m * 16 + l16) * NEMBD + 32 + quad * 8);
        aqB[m][0] = *(const short8*)(Qb + (size_t)(q0B + m * 16 + l16) * NEMBD + quad * 8);
        aqB[m][1] = *(const short8*)(Qb + (size_t)(q0B + m * 16 + l16) * NEMBD + 32 + quad * 8);
    }

    f32x4 accA[2][4], accB[2][4];
#pragma unroll
    for (int m = 0; m < 2; m++)
#pragma unroll
        for (int n = 0; n < 4; n++) {
            accA[m][n] = (f32x4){0.f, 0.f, 0.f, 0.f};
            accB[m][n] = (f32x4){0.f, 0.f, 0.f, 0.f};
        }
    float lsA[2][4] = {{0.f, 0.f, 0.f, 0.f}, {0.f, 0.f, 0.f, 0.f}};
    float lsB[2][4] = {{0.f, 0.f, 0.f, 0.f}, {0.f, 0.f, 0.f, 0.f}};

    const int rsub = lane >> 3;
    const int csw8 = ((lane & 7) ^ rsub) * 8;
    const int swr = l16 & 7;
    u16* pw = &Pl[wave * 64 * 72];

    const int ktiles  = 2 * qtB + 2;                // B covers the full key range
    const int ktilesA = 2 * qtA + 2;                // A active only this far

    // stage one 64-key K/V tile into buffer bufi (each wave: 16 rows of each)
    auto stageKV = [&](int kbase, int bufi) {
#pragma unroll
        for (int j = 0; j < 2; j++) {
            const int g0 = wave * 16 + j * 8;       // 8-row group base
            async_ld16(Kb + (size_t)(kbase + g0 + rsub) * NEMBD + csw8, &Kl[bufi][g0 * 64]);
            async_ld16(Vb + (size_t)(g0 + rsub) * LL + kbase + csw8, &Vt[bufi][g0 * 64]);
        }
    };

    // QK^T + exp + P write for one tile (Pl region pwT)
    auto qk = [&](const short8 (&aq)[2][2], int q0w, int kbase, const u16* KlC,
                  u16* pwT, float (&lsum)[2][4]) {
#pragma unroll
        for (int m = 0; m < 2; m++) {
            const int qlo = q0w + m * 16;
            if (kbase > qlo + 15) continue;         // fully masked (wave-uniform)
            const bool dg = (kbase + 63 > qlo);
#pragma unroll
            for (int s = 0; s < 4; s++) {
                const int key = s * 16 + l16;
                const short8 bk0 = *(const short8*)&KlC[key * 64 + ((quad ^ swr) * 8)];
                const short8 bk1 = *(const short8*)&KlC[key * 64 + (((quad + 4) ^ swr) * 8)];
                f32x4 ss = (f32x4){0.f, 0.f, 0.f, 0.f};
                ss = __builtin_amdgcn_mfma_f32_16x16x32_bf16(aq[m][0], bk0, ss, 0, 0, 0);
                ss = __builtin_amdgcn_mfma_f32_16x16x32_bf16(aq[m][1], bk1, ss, 0, 0, 0);
#pragma unroll
                for (int r = 0; r < 4; r++) {
                    float e = __expf(ss[r]);
                    if (dg && (kbase + key > qlo + quad * 4 + r)) e = 0.f;
                    lsum[m][r] += e;
                    pwT[(m * 16 + quad * 4 + r) * 72 + key] = f2bf(e);
                }
            }
        }
    };

    // P x V accumulate for one tile
    auto pv = [&](f32x4 (&acc)[2][4], int q0w, int kbase, const u16* pwT,
                  const short8 (&bv)[4][2]) {
#pragma unroll
        for (int m = 0; m < 2; m++) {
            if (kbase > q0w + m * 16 + 15) continue;
            const short8 ap0 = *(const short8*)&pwT[(m * 16 + l16) * 72 + quad * 8];
            const short8 ap1 = *(const short8*)&pwT[(m * 16 + l16) * 72 + 32 + quad * 8];
#pragma unroll
            for (int n = 0; n < 4; n++) {
                acc[m][n] = __builtin_amdgcn_mfma_f32_16x16x32_bf16(ap0, bv[n][0], acc[m][n], 0, 0, 0);
                acc[m][n] = __builtin_amdgcn_mfma_f32_16x16x32_bf16(ap1, bv[n][1], acc[m][n], 0, 0, 0);
            }
        }
    };

    // prologue: stage kt=0 into buf 0
    stageKV(0, 0);
    WAIT_ALL();
    __syncthreads();

    int cur = 0;
    for (int kt = 0; kt < ktiles; kt++) {
        const int kbase = kt * 64;
        // prefetch next tile into the other buffer BEFORE compute
        if (kt + 1 < ktiles) stageKV(kbase + 64, cur ^ 1);

        const u16* KlC = &Kl[cur][0];
        const u16* VtC = &Vt[cur][0];

        qk(aqB, q0B, kbase, KlC, pw + 32 * 72, lsB);
        if (kt < ktilesA) qk(aqA, q0A, kbase, KlC, pw, lsA);
        asm volatile("s_waitcnt lgkmcnt(0)" ::: "memory");  // wave-private P write->read

        const bool actB = (kbase <= q0B + 31);
        const bool actA = (kt < ktilesA) && (kbase <= q0A + 31);
        if (actA || actB) {
            short8 bv[4][2];
#pragma unroll
            for (int n = 0; n < 4; n++) {
                const int drow = (n * 16 + l16) * 64;
                bv[n][0] = *(const short8*)&VtC[drow + ((quad ^ swr) * 8)];
                bv[n][1] = *(const short8*)&VtC[drow + (((quad + 4) ^ swr) * 8)];
            }
            __builtin_amdgcn_s_setprio(1);
            if (actB) pv(accB, q0B, kbase, pw + 32 * 72, bv);
            if (actA) pv(accA, q0A, kbase, pw, bv);
            __builtin_amdgcn_s_setprio(0);
        }

        WAIT_ALL();                                 // drain prefetch (overlapped w/ compute)
        __syncthreads();                            // all waves done with buf[cur]
        cur ^= 1;
    }

    u16* Yb = Yp + (size_t)b * LL * NEMBD + h * HDIM;
    auto epi = [&](f32x4 (&acc)[2][4], float (&lsum)[2][4], int q0w) {
#pragma unroll
        for (int m = 0; m < 2; m++) {
#pragma unroll
            for (int r = 0; r < 4; r++) {
                float lr = lsum[m][r];
                lr += __shfl_xor(lr, 1); lr += __shfl_xor(lr, 2);
                lr += __shfl_xor(lr, 4); lr += __shfl_xor(lr, 8);
                const float inv = 1.f / lr;
                const int q = q0w + m * 16 + quad * 4 + r;
#pragma unroll
                for (int n = 0; n < 4; n++)
                    Yb[(size_t)q * NEMBD + n * 16 + l16] = f2bf(acc[m][n][r] * inv);
            }
        }
    };
    epi(accA, lsA, q0A);
    epi(accB, lsB, q0B);
}

// ------------------------------------------------------------------
extern "C" void kernel_launch(void* const* d_in, const int* in_sizes, int n_in,
                              void* d_out, int out_size, void* d_ws, size_t ws_size,
                              hipStream_t stream)
{
    const float* key   = (const float*)d_in[0];
    const float* value = (const float*)d_in[1];
    const float* query = (const float*)d_in[2];
    const float* Wk = (const float*)d_in[3];
    const float* bk = (const float*)d_in[4];
    const float* Wq = (const float*)d_in[5];
    const float* bq = (const float*)d_in[6];
    const float* Wv = (const float*)d_in[7];
    const float* bv = (const float*)d_in[8];
    const float* Wp = (const float*)d_in[9];
    const float* bp = (const float*)d_in[10];

    u16* ws = (u16*)d_ws;
    u16* qb = ws + OFF_QB;                       // Q proj; also attn output (alias-safe)
    u16* kb = (u16*)d_out;                       // K proj in d_out
    u16* vtg = (u16*)d_out + (1u << 23);         // V^T [b][h][d][key] in d_out

    const bool preX = ws_size >= WS_NEED_PRE;    // constant across calls -> graph-safe

    cvt_all<<<preX ? 28676 : 4100, 256, 0, stream>>>(
        Wq, Wk, Wv, Wp, bq, bk, bv, bp, query, key, value, ws);

    if (preX) {
        const u16* xq = ws + OFF_X;
        const u16* xk = ws + OFF_X + (1u << 23);
        const u16* xv = ws + OFF_X + (2u << 23);
        gemm_qkv_b<<<dim3(8, 64, 3), 256, 0, stream>>>(xq, xk, xv, ws, qb, kb, vtg);
    } else {
        gemm_qkv_f<<<dim3(8, 64, 3), 256, 0, stream>>>(query, key, value, ws, qb, kb, vtg);
    }

    attn_fused<<<dim3(4, 128), 256, 0, stream>>>(qb, kb, vtg, qb);

    gemm_out_k<<<dim3(8, 64), 256, 0, stream>>>(qb, ws, (float*)d_out);
}